// Round 1
// baseline (309.116 us; speedup 1.0000x reference)
//
#include <hip/hip_runtime.h>
#include <math.h>

// Problem constants
#define B      2048
#define N      100000
#define NPAD2  100352   // 98 * 1024
#define JGRP2  98
#define JT4    16       // 64-col j-steps per filter block (16*64 = 1024 cols)
#define DD     64
#define HH     256
#define KK     20
#define SAMPLE 8192
#define CAP    1024
#define SSEL   512
#define SLACK  1.5f
#define LCAP   8        // per-row LDS bucket slots (lambda ~2.5 per block)
#define RING_D 3        // LDS ring depth (stage 2 steps ahead)

#define INF_F (__builtin_inff())

typedef __bf16 bf16x8 __attribute__((ext_vector_type(8)));
typedef __bf16 bf16x4 __attribute__((ext_vector_type(4)));
typedef float  floatx4 __attribute__((ext_vector_type(4)));
union U16 { uint4 u; bf16x8 v; };

__device__ __forceinline__ float wsum64(float v) {
    #pragma unroll
    for (int o = 32; o > 0; o >>= 1) v += __shfl_xor(v, o, 64);
    return v;
}
__device__ __forceinline__ int wsum64i(int v) {
    #pragma unroll
    for (int o = 32; o > 0; o >>= 1) v += __shfl_xor(v, o, 64);
    return v;
}

// async global->LDS, 16B per lane; LDS dest is wave-uniform base + lane*16
__device__ __forceinline__ void glds16(const void* g, void* l) {
    __builtin_amdgcn_global_load_lds(
        (const __attribute__((address_space(1))) unsigned*)g,
        (__attribute__((address_space(3))) unsigned*)l, 16, 0, 0);
}

// ---------------- fused setup: data_prep + prep + mlp (block-range dispatch) -
// blocks [0, 6272)            : data_prep (dnorm, dnh, d_hi)
// blocks [6272, 6784)         : prep (xs, xnorm, xs_h, cnt=0), 4 rows/block
// blocks [6784, 7040)         : mlp, 8 rows/block
#define NB_DATA 6272
#define NB_PREP 512
#define NB_MLP  256
__global__ __launch_bounds__(256) void setup_all(const float* __restrict__ z,
                                                 const float* __restrict__ tp,
                                                 const float* __restrict__ data,
                                                 const float* __restrict__ W1,
                                                 const float* __restrict__ b1,
                                                 const float* __restrict__ W2,
                                                 const float* __restrict__ b2,
                                                 float* __restrict__ xs,
                                                 float* __restrict__ xnorm,
                                                 __bf16* __restrict__ xs_h,
                                                 int* __restrict__ cnt,
                                                 float* __restrict__ dnorm,
                                                 float* __restrict__ dnh,
                                                 __bf16* __restrict__ d_hi,
                                                 float* __restrict__ xdot) {
    int bx = blockIdx.x, tid = threadIdx.x;
    if (bx < NB_DATA) {
        int gt = bx * 256 + tid;
        int j = gt >> 4, l = gt & 15;
        float4 v = make_float4(0.f, 0.f, 0.f, 0.f);
        if (j < N)
            v = reinterpret_cast<const float4*>(data + (size_t)j * 64)[l];
        bf16x4 o;
        o.x = (__bf16)v.x; o.y = (__bf16)v.y; o.z = (__bf16)v.z; o.w = (__bf16)v.w;
        *reinterpret_cast<bf16x4*>(d_hi + (size_t)j * 64 + l * 4) = o;
        float s = v.x * v.x + v.y * v.y + v.z * v.z + v.w * v.w;
        #pragma unroll
        for (int o2 = 1; o2 < 16; o2 <<= 1) s += __shfl_xor(s, o2, 64);
        if (l == 0) {
            dnorm[j] = (j < N) ? s : INF_F;
            dnh[j]   = (j < N) ? 0.5f * s : INF_F;
        }
    } else if (bx < NB_DATA + NB_PREP) {
        int row = (bx - NB_DATA) * 4 + (tid >> 6);
        int d = tid & 63;
        float v = z[row * 66 + d];
        xs[row * 64 + d] = v;
        xs_h[row * 64 + d] = (__bf16)v;
        float s = wsum64(v * v);
        if (d == 0) xnorm[row] = s;
        if (d == 1) cnt[row] = 0;
    } else {
        __shared__ float sin_[8][65];
        __shared__ float shid[8][HH];
        int row0 = (bx - NB_DATA - NB_PREP) * 8;
        float tval = tp[0];
        for (int idx = tid; idx < 8 * 64; idx += 256) {
            int r = idx >> 6, d = idx & 63;
            sin_[r][d] = z[(row0 + r) * 66 + d];
        }
        if (tid < 8) sin_[tid][64] = tval;
        __syncthreads();
        int h = tid;
        float acc[8];
        #pragma unroll
        for (int r = 0; r < 8; ++r) acc[r] = b1[h];
        for (int i = 0; i < 65; ++i) {
            float wv = W1[i * HH + h];
            #pragma unroll
            for (int r = 0; r < 8; ++r) acc[r] = fmaf(sin_[r][i], wv, acc[r]);
        }
        #pragma unroll
        for (int r = 0; r < 8; ++r) shid[r][h] = fmaxf(acc[r], 0.f);
        __syncthreads();
        int d = tid & 63, rb = tid >> 6;
        for (int rr = rb; rr < 8; rr += 4) {
            float a = b2[d];
            #pragma unroll 8
            for (int hh2 = 0; hh2 < HH; ++hh2)
                a = fmaf(shid[rr][hh2], W2[hh2 * 64 + d], a);
            xdot[(size_t)(row0 + rr) * 64 + d] = a;
        }
    }
}

// --------------------- approx sample GEMM -> u16 keys (top 16 bits of fp32) -
__global__ __launch_bounds__(256) void sample_gemm(const __bf16* __restrict__ xs_h,
                                                   const __bf16* __restrict__ d_hi,
                                                   const float* __restrict__ xnorm,
                                                   const float* __restrict__ dnorm,
                                                   unsigned short* __restrict__ samp16) {
    int tid = threadIdx.x;
    int m0 = blockIdx.x * 128;
    int jbase = blockIdx.y * 128;
    int wv = tid >> 6, wm = wv & 1, wn = wv >> 1;
    int lane = tid & 63, l16 = lane & 15, quad = lane >> 4;

    bf16x8 af[2][4], bfr[2][4];
    #pragma unroll
    for (int s = 0; s < 2; ++s)
        #pragma unroll
        for (int mt = 0; mt < 4; ++mt) {
            int row = m0 + wm * 64 + mt * 16 + l16;
            U16 u; u.u = reinterpret_cast<const uint4*>(xs_h + (size_t)row * 64)[s * 4 + quad];
            af[s][mt] = u.v;
        }
    #pragma unroll
    for (int s = 0; s < 2; ++s)
        #pragma unroll
        for (int nt = 0; nt < 4; ++nt) {
            int jr = jbase + wn * 64 + nt * 16 + l16;
            U16 u; u.u = reinterpret_cast<const uint4*>(d_hi + (size_t)jr * 64)[s * 4 + quad];
            bfr[s][nt] = u.v;
        }
    float dn[4], sxn[4][4];
    #pragma unroll
    for (int nt = 0; nt < 4; ++nt)
        dn[nt] = dnorm[jbase + wn * 64 + nt * 16 + l16];
    #pragma unroll
    for (int mt = 0; mt < 4; ++mt)
        #pragma unroll
        for (int rg = 0; rg < 4; ++rg)
            sxn[mt][rg] = xnorm[m0 + wm * 64 + mt * 16 + quad * 4 + rg];

    floatx4 acc[4][4];
    #pragma unroll
    for (int mt = 0; mt < 4; ++mt)
        #pragma unroll
        for (int nt = 0; nt < 4; ++nt)
            acc[mt][nt] = (floatx4){0.f, 0.f, 0.f, 0.f};
    #pragma unroll
    for (int s = 0; s < 2; ++s)
        #pragma unroll
        for (int mt = 0; mt < 4; ++mt)
            #pragma unroll
            for (int nt = 0; nt < 4; ++nt)
                acc[mt][nt] = __builtin_amdgcn_mfma_f32_16x16x32_bf16(
                    af[s][mt], bfr[s][nt], acc[mt][nt], 0, 0, 0);

    #pragma unroll
    for (int mt = 0; mt < 4; ++mt)
        #pragma unroll
        for (int nt = 0; nt < 4; ++nt) {
            floatx4 a4 = acc[mt][nt];
            int j = jbase + wn * 64 + nt * 16 + l16;
            #pragma unroll
            for (int rg = 0; rg < 4; ++rg) {
                int row = m0 + wm * 64 + mt * 16 + quad * 4 + rg;
                float sq = fmaf(a4[rg], -2.f, dn[nt]) + sxn[mt][rg];
                samp16[(size_t)row * SAMPLE + j] =
                    (unsigned short)(__float_as_uint(fmaxf(sq, 0.f)) >> 16);
            }
        }
}

// --------------- thr select: one wave per row, bitwise bisection on u16 keys
// thr = float bits ((k20+1)<<16) -- ceiling of the 20th-smallest key's bin,
// an upper bound on the 20th-smallest approx sample sq. Safe: chain only
// needs thr >= (20th approx sample sq) - 0; ceiling only loosens.
__global__ __launch_bounds__(256) void thr_select(const unsigned short* __restrict__ samp16,
                                                  float* __restrict__ thr) {
    int wv = threadIdx.x >> 6, lane = threadIdx.x & 63;
    int row = blockIdx.x * 4 + wv;
    const unsigned* sp = reinterpret_cast<const unsigned*>(samp16 + (size_t)row * SAMPLE);
    unsigned w[64];
    #pragma unroll
    for (int i = 0; i < 64; ++i) w[i] = sp[lane + i * 64];
    unsigned res = 0;
    for (int b = 15; b >= 0; --b) {
        unsigned cand = res | (1u << b);
        int c = 0;
        #pragma unroll
        for (int i = 0; i < 64; ++i) {
            c += ((w[i] & 0xFFFFu) < cand);
            c += ((w[i] >> 16) < cand);
        }
        c = wsum64i(c);
        if (c <= KK - 1) res = cand;   // rank 19 (0-indexed) = 20th smallest
    }
    if (lane == 0) thr[row] = __uint_as_float((res + 1u) << 16);
}

// ------ bf16 MFMA filter v2: LDS ring buffer (depth 3, staged 2 ahead) via
// global_load_lds with XOR-pre-swizzled source (linear LDS write == swizzled
// layout), counted vmcnt(4) so loads stay in flight across barriers.
// pass <=> D >= dnh[j] with D = dot_b + 0.5*(thr+2S-xn); same chain as before.
__device__ __forceinline__ void filter_step(
    const char* ringslot, const float* sdnh, int t, int jstart, int m0,
    int wn, int l16, int jr0, const int off16[2][2],
    const bf16x8 af[2][4], const float scv[4][4],
    const float* sts, int* lcnt, float (*lbd)[LCAP + 1], int (*lbj)[LCAP + 1],
    int* __restrict__ cnt, float* __restrict__ bufd, int* __restrict__ bufi) {
    const uint4* bsrc = reinterpret_cast<const uint4*>(ringslot);
    U16 u00, u01, u10, u11;
    u00.u = bsrc[off16[0][0]];
    u01.u = bsrc[off16[0][1]];
    u10.u = bsrc[off16[1][0]];
    u11.u = bsrc[off16[1][1]];
    float dd0 = sdnh[t * 64 + jr0];
    float dd1 = sdnh[t * 64 + jr0 + 16];

    floatx4 acc[4][2];
    #pragma unroll
    for (int mt = 0; mt < 4; ++mt) {
        floatx4 cv = (floatx4){scv[mt][0], scv[mt][1], scv[mt][2], scv[mt][3]};
        acc[mt][0] = cv;
        acc[mt][1] = cv;
    }
    __builtin_amdgcn_s_setprio(1);
    #pragma unroll
    for (int mt = 0; mt < 4; ++mt) {
        acc[mt][0] = __builtin_amdgcn_mfma_f32_16x16x32_bf16(af[0][mt], u00.v, acc[mt][0], 0, 0, 0);
        acc[mt][1] = __builtin_amdgcn_mfma_f32_16x16x32_bf16(af[0][mt], u01.v, acc[mt][1], 0, 0, 0);
    }
    #pragma unroll
    for (int mt = 0; mt < 4; ++mt) {
        acc[mt][0] = __builtin_amdgcn_mfma_f32_16x16x32_bf16(af[1][mt], u10.v, acc[mt][0], 0, 0, 0);
        acc[mt][1] = __builtin_amdgcn_mfma_f32_16x16x32_bf16(af[1][mt], u11.v, acc[mt][1], 0, 0, 0);
    }
    __builtin_amdgcn_s_setprio(0);

    int jb = jstart + t * 64;
    int wm_mloc = 0; // folded below via m0-relative mloc
    (void)wm_mloc;
    #pragma unroll
    for (int nt = 0; nt < 2; ++nt) {
        int j = jb + wn * 32 + nt * 16 + l16;
        float dd = nt ? dd1 : dd0;      // INF for pad cols -> never pass
        #pragma unroll
        for (int mt = 0; mt < 4; ++mt) {
            floatx4 a4 = acc[mt][nt];
            float mx = fmaxf(fmaxf(a4[0], a4[1]), fmaxf(a4[2], a4[3]));
            if (mx >= dd) {
                #pragma unroll
                for (int rg = 0; rg < 4; ++rg) {
                    if (a4[rg] >= dd) {
                        // mloc encodes wm via off16-independent path: caller
                        // passes jr0/off16 built from wn; wm folded into scv
                        // row constants and mloc base (see caller's mbase).
                        int mloc = ((off16[0][0] >> 31) & 0); // always 0; keep shape
                        (void)mloc;
                        // real mloc computed by caller-provided base:
                        // stored in lcnt index space [0,128)
                        int mrow = (int)(sts - sts); (void)mrow;
                        // NOTE: actual push below uses precomputed mbase in sts
                        // indexing; see macro-free inline in caller.
                        // (unreachable placeholder removed at compile time)
                    }
                }
            }
        }
    }
}

// NOTE: filter_step above kept minimal for the MFMA core is NOT used for the
// candidate push (which needs wm/quad). The full step including the push is
// inlined in the kernel body below; filter_step is unused.
// (Kept deleted from call path.)

__global__ __launch_bounds__(256, 4) void gemm_filter(const __bf16* __restrict__ xs_h,
                                                      const __bf16* __restrict__ d_hi,
                                                      const float* __restrict__ xnorm,
                                                      const float* __restrict__ dnh,
                                                      const float* __restrict__ thr,
                                                      int* __restrict__ cnt,
                                                      float* __restrict__ bufd,
                                                      int* __restrict__ bufi) {
    __shared__ float sts[128];           // thr+2S
    __shared__ int   lcnt[128];
    __shared__ float lbd[128][LCAP + 1];
    __shared__ int   lbj[128][LCAP + 1];
    __shared__ __align__(16) char  ring[RING_D * 8192];   // B-tile ring, 64 rows x 128B
    __shared__ __align__(16) float sdnh[JT4 * 64];        // dnh for all 1024 cols

    int tid = threadIdx.x;
    int m0 = blockIdx.x * 128;
    int jstart = blockIdx.y * (JT4 * 64);
    int wv = tid >> 6, wm = wv & 1, wn = wv >> 1;   // 2x2 wave grid
    int lane = tid & 63, l16 = lane & 15, quad = lane >> 4;

    if (tid < 128) {
        sts[tid] = thr[m0 + tid] + 2.0f * SLACK;
        lcnt[tid] = 0;
    }
    // persistent A fragments
    bf16x8 af[2][4];
    #pragma unroll
    for (int s = 0; s < 2; ++s)
        #pragma unroll
        for (int mt = 0; mt < 4; ++mt) {
            int row = m0 + wm * 64 + mt * 16 + l16;
            U16 u; u.u = reinterpret_cast<const uint4*>(xs_h + (size_t)row * 64)[s * 4 + quad];
            af[s][mt] = u.v;
        }
    // acc-init constants: 0.5*(thr+2S-xn) per (mt,rg)
    float scv[4][4];
    #pragma unroll
    for (int mt = 0; mt < 4; ++mt)
        #pragma unroll
        for (int rg = 0; rg < 4; ++rg) {
            int mg = m0 + wm * 64 + mt * 16 + quad * 4 + rg;
            scv[mt][rg] = 0.5f * (thr[mg] + 2.0f * SLACK - xnorm[mg]);
        }

    // per-lane swizzled staging source: instruction w covers rows w*8+(lane>>3),
    // chunk (lane&7)^(row&7); LDS dest is linear (base + lane*16).
    int r8 = lane >> 3, c8 = lane & 7;
    const char* gB = (const char*)d_hi + (size_t)jstart * 128
                   + (size_t)(wv * 2048 + r8 * 128 + ((c8 ^ r8) << 4));
    // swizzled fragment read offsets (16B units within a ring slot)
    int off16[2][2];
    #pragma unroll
    for (int s = 0; s < 2; ++s)
        #pragma unroll
        for (int nt = 0; nt < 2; ++nt) {
            int row = wn * 32 + nt * 16 + l16;
            off16[s][nt] = row * 8 + ((s * 4 + quad) ^ (l16 & 7));
        }
    int jr0 = wn * 32 + l16;

    // keep prologue register loads ordered before the async stages (FIFO)
    asm volatile("" ::: "memory");

    // ---- prologue async stages: dnh table (4KB, linear) + steps 0,1
    glds16((const char*)dnh + (size_t)jstart * 4 + (size_t)(wv * 1024 + lane * 16),
           (char*)sdnh + wv * 1024);
    #pragma unroll
    for (int p = 0; p < 2; ++p) {
        glds16(gB + (size_t)p * 8192,        ring + p * 8192 + wv * 2048);
        glds16(gB + (size_t)p * 8192 + 1024, ring + p * 8192 + wv * 2048 + 1024);
    }
    asm volatile("s_waitcnt lgkmcnt(0)" ::: "memory");  // sts/lcnt writes done

    int sc = 0;            // slot of step t
    int sp = 2;            // slot of step t+2
    for (int t = 0; t < JT4; ++t) {
        if (t < JT4 - 2) {
            __builtin_amdgcn_s_barrier();        // all waves done step t-1
            asm volatile("" ::: "memory");
            // stage step t+2 (slot sp != any slot readable by laggards)
            glds16(gB + (size_t)(t + 2) * 8192,        ring + sp * 8192 + wv * 2048);
            glds16(gB + (size_t)(t + 2) * 8192 + 1024, ring + sp * 8192 + wv * 2048 + 1024);
            asm volatile("s_waitcnt vmcnt(4)" ::: "memory");   // my stage(t) landed
        } else if (t == JT4 - 2) {
            asm volatile("s_waitcnt vmcnt(2)" ::: "memory");
        } else {
            asm volatile("s_waitcnt vmcnt(0)" ::: "memory");
        }
        __builtin_amdgcn_s_barrier();            // everyone's stage(t) visible
        asm volatile("" ::: "memory");

        // ---------------- compute step t from ring slot sc ----------------
        {
            const uint4* bsrc = reinterpret_cast<const uint4*>(ring + sc * 8192);
            U16 u00, u01, u10, u11;
            u00.u = bsrc[off16[0][0]];
            u01.u = bsrc[off16[0][1]];
            u10.u = bsrc[off16[1][0]];
            u11.u = bsrc[off16[1][1]];
            float dd0 = sdnh[t * 64 + jr0];
            float dd1 = sdnh[t * 64 + jr0 + 16];

            floatx4 acc[4][2];
            #pragma unroll
            for (int mt = 0; mt < 4; ++mt) {
                floatx4 cv = (floatx4){scv[mt][0], scv[mt][1], scv[mt][2], scv[mt][3]};
                acc[mt][0] = cv;
                acc[mt][1] = cv;
            }
            __builtin_amdgcn_s_setprio(1);
            #pragma unroll
            for (int mt = 0; mt < 4; ++mt) {
                acc[mt][0] = __builtin_amdgcn_mfma_f32_16x16x32_bf16(af[0][mt], u00.v, acc[mt][0], 0, 0, 0);
                acc[mt][1] = __builtin_amdgcn_mfma_f32_16x16x32_bf16(af[0][mt], u01.v, acc[mt][1], 0, 0, 0);
            }
            #pragma unroll
            for (int mt = 0; mt < 4; ++mt) {
                acc[mt][0] = __builtin_amdgcn_mfma_f32_16x16x32_bf16(af[1][mt], u10.v, acc[mt][0], 0, 0, 0);
                acc[mt][1] = __builtin_amdgcn_mfma_f32_16x16x32_bf16(af[1][mt], u11.v, acc[mt][1], 0, 0, 0);
            }
            __builtin_amdgcn_s_setprio(0);

            int jb = jstart + t * 64;
            #pragma unroll
            for (int nt = 0; nt < 2; ++nt) {
                int j = jb + wn * 32 + nt * 16 + l16;
                float dd = nt ? dd1 : dd0;     // INF for pad cols -> never pass
                #pragma unroll
                for (int mt = 0; mt < 4; ++mt) {
                    floatx4 a4 = acc[mt][nt];
                    float mx = fmaxf(fmaxf(a4[0], a4[1]), fmaxf(a4[2], a4[3]));
                    if (mx >= dd) {
                        #pragma unroll
                        for (int rg = 0; rg < 4; ++rg) {
                            if (a4[rg] >= dd) {
                                int mloc = wm * 64 + mt * 16 + quad * 4 + rg;
                                float delta = 2.0f * (dd - a4[rg]);  // sqb - (thr+2S)
                                int pos = atomicAdd(&lcnt[mloc], 1);
                                if (pos < LCAP) {
                                    lbd[mloc][pos] = delta;
                                    lbj[mloc][pos] = j;
                                } else {                              // rare overflow
                                    int row = m0 + mloc;
                                    int gp = atomicAdd(&cnt[row], 1);
                                    if (gp < CAP) {
                                        bufd[(size_t)row * CAP + gp] = sts[mloc] + delta;
                                        bufi[(size_t)row * CAP + gp] = j;
                                    }
                                }
                            }
                        }
                    }
                }
            }
        }
        sp = (sp == RING_D - 1) ? 0 : sp + 1;
        sc = (sc == RING_D - 1) ? 0 : sc + 1;
    }
    __syncthreads();
    if (tid < 128) {
        int c = lcnt[tid];
        if (c > LCAP) c = LCAP;
        if (c > 0) {
            int row = m0 + tid;
            float ts = sts[tid];
            int base = atomicAdd(&cnt[row], c);
            for (int i = 0; i < c; ++i) {
                int gp = base + i;
                if (gp < CAP) {
                    bufd[(size_t)row * CAP + gp] = ts + lbd[tid][i];
                    bufi[(size_t)row * CAP + gp] = lbj[tid][i];
                }
            }
        }
    }
}

// --------------------------------------------------------- select + finish --
__global__ __launch_bounds__(64) void select_finish(const float* __restrict__ bufd,
                                                    const int* __restrict__ bufi,
                                                    const int* __restrict__ cnt,
                                                    const float* __restrict__ xs,
                                                    const float* __restrict__ xnorm,
                                                    const float* __restrict__ dnorm,
                                                    const float* __restrict__ data,
                                                    const float* __restrict__ xdot,
                                                    const float* __restrict__ vel,
                                                    float* __restrict__ out) {
    __shared__ float sd[CAP];
    __shared__ int   si[CAP];
    __shared__ float sx[64];
    __shared__ float se[SSEL];
    __shared__ int   sj[SSEL];
    __shared__ int   scnt;
    __shared__ float seld[KK];
    __shared__ int   seli[KK];
    __shared__ float selw[KK];
    int row = blockIdx.x, lane = threadIdx.x;
    int n = cnt[row];
    if (n > CAP) n = CAP;
    for (int i = lane; i < n; i += 64) {
        sd[i] = bufd[(size_t)row * CAP + i];
        si[i] = bufi[(size_t)row * CAP + i];
    }
    sx[lane] = xs[row * 64 + lane];
    if (lane == 0) scnt = 0;
    __syncthreads();

    // T = exact 20th smallest of clamped approx sq -- bitwise bisection
    unsigned res = 0;
    for (int b = 30; b >= 0; --b) {
        unsigned cand = res | (1u << b);
        int c = 0;
        for (int i = lane; i < n; i += 64)
            c += (__float_as_uint(fmaxf(sd[i], 0.f)) < cand);
        c = wsum64i(c);
        if (c <= KK - 1) res = cand;
    }
    float T = __uint_as_float(res);

    // band {approx <= T + 2*SLACK} is a superset of the exact top-20
    for (int i = lane; i < n; i += 64) {
        if (sd[i] <= T + 2.0f * SLACK) {
            int q = atomicAdd(&scnt, 1);
            if (q < SSEL) sj[q] = si[i];
        }
    }
    __syncthreads();
    int m = scnt < SSEL ? scnt : SSEL;
    // exact fp32 recompute (bit-identical chain: sequential fmaf, k ascending)
    for (int c = lane; c < m; c += 64) {
        int j = sj[c];
        const float4* dp = reinterpret_cast<const float4*>(data + (size_t)j * 64);
        float dot = 0.f;
        #pragma unroll
        for (int kb = 0; kb < 16; ++kb) {
            float4 q = dp[kb];
            dot = fmaf(sx[kb * 4 + 0], q.x, dot);
            dot = fmaf(sx[kb * 4 + 1], q.y, dot);
            dot = fmaf(sx[kb * 4 + 2], q.z, dot);
            dot = fmaf(sx[kb * 4 + 3], q.w, dot);
        }
        se[c] = xnorm[row] + dnorm[j] - 2.0f * dot;
    }
    __syncthreads();
    // exact top-20, tie-break smaller index (matches lax.top_k)
    for (int k = 0; k < KK; ++k) {
        float v = INF_F; int id = 0x7fffffff; int p = -1;
        for (int i = lane; i < m; i += 64) {
            float x = se[i]; int xi = sj[i];
            if (x < v || (x == v && xi < id)) { v = x; id = xi; p = i; }
        }
        #pragma unroll
        for (int o = 32; o > 0; o >>= 1) {
            float ov = __shfl_xor(v, o, 64);
            int oid = __shfl_xor(id, o, 64);
            int op  = __shfl_xor(p, o, 64);
            if (ov < v || (ov == v && oid < id)) { v = ov; id = oid; p = op; }
        }
        if (lane == 0) {
            seld[k] = v; seli[k] = id;
            if (p >= 0) se[p] = INF_F;
        }
        __syncthreads();
    }
    float d20 = sqrtf(fmaxf(seld[KK - 1], 1e-30f));
    float h = fmaxf(d20, 1e-12f);
    float wk = 0.f;
    if (lane < KK) {
        float dd = sqrtf(fmaxf(seld[lane], 1e-30f));
        wk = expf(-(dd * dd) / (2.f * h * h));
    }
    float tot = wsum64(wk) + 1e-12f;
    if (lane < KK) selw[lane] = wk / tot;
    __syncthreads();
    float u = 0.f;
    #pragma unroll
    for (int k = 0; k < KK; ++k)
        u = fmaf(selw[k], vel[(size_t)seli[k] * 64 + lane], u);
    float xd = xdot[(size_t)row * 64 + lane];
    float du  = wsum64(u * xd);
    float nu2 = wsum64(u * u);
    float nx2 = wsum64(xd * xd);
    float l2  = wsum64((u - xd) * (u - xd));
    float nu = fmaxf(sqrtf(nu2), 1e-8f);
    float nx = fmaxf(sqrtf(nx2), 1e-8f);
    out[(size_t)row * 66 + lane] = xd;
    if (lane == 0) {
        out[(size_t)row * 66 + 64] = 1.f - du / (nu * nx);
        out[(size_t)row * 66 + 65] = l2;
    }
}

// ---------------------------------------------------------------------------
extern "C" void kernel_launch(void* const* d_in, const int* in_sizes, int n_in,
                              void* d_out, int out_size, void* d_ws, size_t ws_size,
                              hipStream_t stream) {
    const float* t_   = (const float*)d_in[0];
    const float* z    = (const float*)d_in[1];
    const float* data = (const float*)d_in[2];
    const float* vel  = (const float*)d_in[3];
    const float* W1   = (const float*)d_in[4];
    const float* b1   = (const float*)d_in[5];
    const float* W2   = (const float*)d_in[6];
    const float* b2   = (const float*)d_in[7];
    float* out = (float*)d_out;

    // workspace layout (floats, 16B-aligned); total ~47 MB
    float*  xs    = (float*)d_ws;                     // 131072
    float*  xnorm = xs + 131072;                      // 2048
    float*  thr   = xnorm + 2048;                     // 2048
    int*    cnt   = (int*)(thr + 2048);               // 2048
    float*  xdot  = (float*)(cnt + 2048);             // 131072
    float*  dnorm = xdot + 131072;                    // 100352
    float*  dnh   = dnorm + NPAD2;                    // 100352
    __bf16* xs_h  = (__bf16*)(dnh + NPAD2);           // 131072 bf16
    __bf16* d_hi  = xs_h + 131072;                    // NPAD2*64 bf16
    unsigned short* samp16 = (unsigned short*)(d_hi + (size_t)NPAD2 * 64); // 2048*8192 u16 = 32MB
    float*  bufd  = (float*)samp16;                   // overlap: samp16 dead first
    int*    bufi  = (int*)(bufd + (size_t)B * CAP);   // 2048*1024

    setup_all<<<NB_DATA + NB_PREP + NB_MLP, 256, 0, stream>>>(
        z, t_, data, W1, b1, W2, b2, xs, xnorm, xs_h, cnt, dnorm, dnh, d_hi, xdot);
    sample_gemm<<<dim3(B / 128, SAMPLE / 128), 256, 0, stream>>>(xs_h, d_hi, xnorm, dnorm, samp16);
    thr_select<<<B / 4, 256, 0, stream>>>(samp16, thr);
    gemm_filter<<<dim3(B / 128, JGRP2), 256, 0, stream>>>(
        xs_h, d_hi, xnorm, dnh, thr, cnt, bufd, bufi);
    select_finish<<<B, 64, 0, stream>>>(bufd, bufi, cnt, xs, xnorm, dnorm, data,
                                        xdot, vel, out);
    (void)ws_size; (void)in_sizes; (void)n_in; (void)out_size;
}

// Round 2
// 300.584 us; speedup vs baseline: 1.0284x; 1.0284x over previous
//
#include <hip/hip_runtime.h>
#include <math.h>

// Problem constants
#define B      2048
#define N      100000
#define NPAD2  100352   // 98 * 1024
#define JGRP2  98
#define JGRP2P 104      // padded window count for XCD swizzle (13*8)
#define JT4    16       // 64-col j-steps per filter block (16*64 = 1024 cols)
#define DD     64
#define HH     256
#define KK     20
#define SAMPLE 8192
#define CAP    1024
#define SSEL   512
#define SLACK  1.5f
#define LCAP   16       // per-row LDS bucket slots (lambda ~2.7 per block)

#define INF_F (__builtin_inff())

typedef __bf16 bf16x8 __attribute__((ext_vector_type(8)));
typedef __bf16 bf16x4 __attribute__((ext_vector_type(4)));
typedef float  floatx4 __attribute__((ext_vector_type(4)));
union U16 { uint4 u; bf16x8 v; };

__device__ __forceinline__ float wsum64(float v) {
    #pragma unroll
    for (int o = 32; o > 0; o >>= 1) v += __shfl_xor(v, o, 64);
    return v;
}
__device__ __forceinline__ int wsum64i(int v) {
    #pragma unroll
    for (int o = 32; o > 0; o >>= 1) v += __shfl_xor(v, o, 64);
    return v;
}

// ---------------- fused setup: data_prep + prep + mlp (block-range dispatch) -
// blocks [0, 6272)            : data_prep (dnorm, dnh, d_hi)
// blocks [6272, 6784)         : prep (xs, xnorm, xs_h, cnt=0), 4 rows/block
// blocks [6784, 7040)         : mlp, 8 rows/block
#define NB_DATA 6272
#define NB_PREP 512
#define NB_MLP  256
__global__ __launch_bounds__(256) void setup_all(const float* __restrict__ z,
                                                 const float* __restrict__ tp,
                                                 const float* __restrict__ data,
                                                 const float* __restrict__ W1,
                                                 const float* __restrict__ b1,
                                                 const float* __restrict__ W2,
                                                 const float* __restrict__ b2,
                                                 float* __restrict__ xs,
                                                 float* __restrict__ xnorm,
                                                 __bf16* __restrict__ xs_h,
                                                 int* __restrict__ cnt,
                                                 float* __restrict__ dnorm,
                                                 float* __restrict__ dnh,
                                                 __bf16* __restrict__ d_hi,
                                                 float* __restrict__ xdot) {
    int bx = blockIdx.x, tid = threadIdx.x;
    if (bx < NB_DATA) {
        int gt = bx * 256 + tid;
        int j = gt >> 4, l = gt & 15;
        float4 v = make_float4(0.f, 0.f, 0.f, 0.f);
        if (j < N)
            v = reinterpret_cast<const float4*>(data + (size_t)j * 64)[l];
        bf16x4 o;
        o.x = (__bf16)v.x; o.y = (__bf16)v.y; o.z = (__bf16)v.z; o.w = (__bf16)v.w;
        *reinterpret_cast<bf16x4*>(d_hi + (size_t)j * 64 + l * 4) = o;
        float s = v.x * v.x + v.y * v.y + v.z * v.z + v.w * v.w;
        #pragma unroll
        for (int o2 = 1; o2 < 16; o2 <<= 1) s += __shfl_xor(s, o2, 64);
        if (l == 0) {
            dnorm[j] = (j < N) ? s : INF_F;
            dnh[j]   = (j < N) ? 0.5f * s : INF_F;
        }
    } else if (bx < NB_DATA + NB_PREP) {
        int row = (bx - NB_DATA) * 4 + (tid >> 6);
        int d = tid & 63;
        float v = z[row * 66 + d];
        xs[row * 64 + d] = v;
        xs_h[row * 64 + d] = (__bf16)v;
        float s = wsum64(v * v);
        if (d == 0) xnorm[row] = s;
        if (d == 1) cnt[row] = 0;
    } else {
        __shared__ float sin_[8][65];
        __shared__ float shid[8][HH];
        int row0 = (bx - NB_DATA - NB_PREP) * 8;
        float tval = tp[0];
        for (int idx = tid; idx < 8 * 64; idx += 256) {
            int r = idx >> 6, d = idx & 63;
            sin_[r][d] = z[(row0 + r) * 66 + d];
        }
        if (tid < 8) sin_[tid][64] = tval;
        __syncthreads();
        int h = tid;
        float acc[8];
        #pragma unroll
        for (int r = 0; r < 8; ++r) acc[r] = b1[h];
        for (int i = 0; i < 65; ++i) {
            float wv = W1[i * HH + h];
            #pragma unroll
            for (int r = 0; r < 8; ++r) acc[r] = fmaf(sin_[r][i], wv, acc[r]);
        }
        #pragma unroll
        for (int r = 0; r < 8; ++r) shid[r][h] = fmaxf(acc[r], 0.f);
        __syncthreads();
        int d = tid & 63, rb = tid >> 6;
        for (int rr = rb; rr < 8; rr += 4) {
            float a = b2[d];
            #pragma unroll 8
            for (int hh2 = 0; hh2 < HH; ++hh2)
                a = fmaf(shid[rr][hh2], W2[hh2 * 64 + d], a);
            xdot[(size_t)(row0 + rr) * 64 + d] = a;
        }
    }
}

// --------------------- approx sample GEMM -> u16 keys (top 16 bits of fp32) -
// 1D grid 1024 = 8 XCD-chunks x 8 windows x 16 row-blocks. XCD swizzle: all
// 16 row-blocks of one 128-col j-window land on one XCD (b%8) so the window
// is fetched into exactly one L2.
__global__ __launch_bounds__(256) void sample_gemm(const __bf16* __restrict__ xs_h,
                                                   const __bf16* __restrict__ d_hi,
                                                   const float* __restrict__ xnorm,
                                                   const float* __restrict__ dnorm,
                                                   unsigned short* __restrict__ samp16) {
    int tid = threadIdx.x;
    int b = blockIdx.x;
    int xcd = b & 7, i = b >> 3;
    int w = (i >> 4) * 8 + xcd;          // 0..63, bijective
    int r = i & 15;
    int m0 = r * 128;
    int jbase = w * 128;
    int wv = tid >> 6, wm = wv & 1, wn = wv >> 1;
    int lane = tid & 63, l16 = lane & 15, quad = lane >> 4;

    bf16x8 af[2][4], bfr[2][4];
    #pragma unroll
    for (int s = 0; s < 2; ++s)
        #pragma unroll
        for (int mt = 0; mt < 4; ++mt) {
            int row = m0 + wm * 64 + mt * 16 + l16;
            U16 u; u.u = reinterpret_cast<const uint4*>(xs_h + (size_t)row * 64)[s * 4 + quad];
            af[s][mt] = u.v;
        }
    #pragma unroll
    for (int s = 0; s < 2; ++s)
        #pragma unroll
        for (int nt = 0; nt < 4; ++nt) {
            int jr = jbase + wn * 64 + nt * 16 + l16;
            U16 u; u.u = reinterpret_cast<const uint4*>(d_hi + (size_t)jr * 64)[s * 4 + quad];
            bfr[s][nt] = u.v;
        }
    float dn[4], sxn[4][4];
    #pragma unroll
    for (int nt = 0; nt < 4; ++nt)
        dn[nt] = dnorm[jbase + wn * 64 + nt * 16 + l16];
    #pragma unroll
    for (int mt = 0; mt < 4; ++mt)
        #pragma unroll
        for (int rg = 0; rg < 4; ++rg)
            sxn[mt][rg] = xnorm[m0 + wm * 64 + mt * 16 + quad * 4 + rg];

    floatx4 acc[4][4];
    #pragma unroll
    for (int mt = 0; mt < 4; ++mt)
        #pragma unroll
        for (int nt = 0; nt < 4; ++nt)
            acc[mt][nt] = (floatx4){0.f, 0.f, 0.f, 0.f};
    #pragma unroll
    for (int s = 0; s < 2; ++s)
        #pragma unroll
        for (int mt = 0; mt < 4; ++mt)
            #pragma unroll
            for (int nt = 0; nt < 4; ++nt)
                acc[mt][nt] = __builtin_amdgcn_mfma_f32_16x16x32_bf16(
                    af[s][mt], bfr[s][nt], acc[mt][nt], 0, 0, 0);

    #pragma unroll
    for (int mt = 0; mt < 4; ++mt)
        #pragma unroll
        for (int nt = 0; nt < 4; ++nt) {
            floatx4 a4 = acc[mt][nt];
            int j = jbase + wn * 64 + nt * 16 + l16;
            #pragma unroll
            for (int rg = 0; rg < 4; ++rg) {
                int row = m0 + wm * 64 + mt * 16 + quad * 4 + rg;
                float sq = fmaf(a4[rg], -2.f, dn[nt]) + sxn[mt][rg];
                samp16[(size_t)row * SAMPLE + j] =
                    (unsigned short)(__float_as_uint(fmaxf(sq, 0.f)) >> 16);
            }
        }
}

// --------------- thr select: one wave per row, bitwise bisection on u16 keys
// thr = float bits ((k20+1)<<16) -- ceiling of the 20th-smallest key's bin,
// an upper bound on the 20th-smallest approx sample sq. Safe: chain only
// needs thr >= (20th approx sample sq) - 0; ceiling only loosens.
__global__ __launch_bounds__(256) void thr_select(const unsigned short* __restrict__ samp16,
                                                  float* __restrict__ thr) {
    int wv = threadIdx.x >> 6, lane = threadIdx.x & 63;
    int row = blockIdx.x * 4 + wv;
    const unsigned* sp = reinterpret_cast<const unsigned*>(samp16 + (size_t)row * SAMPLE);
    unsigned w[64];
    #pragma unroll
    for (int i = 0; i < 64; ++i) w[i] = sp[lane + i * 64];
    unsigned res = 0;
    for (int b = 15; b >= 0; --b) {
        unsigned cand = res | (1u << b);
        int c = 0;
        #pragma unroll
        for (int i = 0; i < 64; ++i) {
            c += ((w[i] & 0xFFFFu) < cand);
            c += ((w[i] >> 16) < cand);
        }
        c = wsum64i(c);
        if (c <= KK - 1) res = cand;   // rank 19 (0-indexed) = 20th smallest
    }
    if (lane == 0) thr[row] = __uint_as_float((res + 1u) << 16);
}

// ------ bf16 MFMA filter: 64x32 wave tile, register double-buffer, 64-col
// steps. pass <=> D >= dnh[j] with D = dot_b + 0.5*(thr+2S-xn)
// (equivalent to sq_b <= thr + 2*SLACK; same guarantee chain as R7/R8)
// 1D grid 1664 = 8 XCD-chunks x 13 windows x 16 row-blocks; all 16 row-blocks
// of one 1024-col j-window land on one XCD (b%8) -> window (128KB) fetched
// into exactly one L2, 15/16 blocks hit L2 instead of HBM. Blocks mapping to
// padded windows w>=98 exit before any side effect (bijective on valid set).
__global__ __launch_bounds__(256, 3) void gemm_filter(const __bf16* __restrict__ xs_h,
                                                      const __bf16* __restrict__ d_hi,
                                                      const float* __restrict__ xnorm,
                                                      const float* __restrict__ dnh,
                                                      const float* __restrict__ thr,
                                                      int* __restrict__ cnt,
                                                      float* __restrict__ bufd,
                                                      int* __restrict__ bufi) {
    __shared__ float sts[128];           // thr+2S
    __shared__ int   lcnt[128];
    __shared__ float lbd[128][LCAP + 1];
    __shared__ int   lbj[128][LCAP + 1];
    int tid = threadIdx.x;
    int b = blockIdx.x;
    int xcd = b & 7, i = b >> 3;
    int w = (i >> 4) * 8 + xcd;          // 0..103
    if (w >= JGRP2) return;              // padded windows: no work, no effects
    int r = i & 15;
    int m0 = r * 128;
    int jstart = w * (JT4 * 64);
    int wv = tid >> 6, wm = wv & 1, wn = wv >> 1;   // 2x2 wave grid
    int lane = tid & 63, l16 = lane & 15, quad = lane >> 4;

    if (tid < 128) {
        sts[tid] = thr[m0 + tid] + 2.0f * SLACK;
        lcnt[tid] = 0;
    }
    // persistent A fragments
    bf16x8 af[2][4];
    #pragma unroll
    for (int s = 0; s < 2; ++s)
        #pragma unroll
        for (int mt = 0; mt < 4; ++mt) {
            int row = m0 + wm * 64 + mt * 16 + l16;
            U16 u; u.u = reinterpret_cast<const uint4*>(xs_h + (size_t)row * 64)[s * 4 + quad];
            af[s][mt] = u.v;
        }
    // acc-init constants: 0.5*(thr+2S-xn) per (mt,rg)
    float scv[4][4];
    #pragma unroll
    for (int mt = 0; mt < 4; ++mt)
        #pragma unroll
        for (int rg = 0; rg < 4; ++rg) {
            int mg = m0 + wm * 64 + mt * 16 + quad * 4 + rg;
            scv[mt][rg] = 0.5f * (thr[mg] + 2.0f * SLACK - xnorm[mg]);
        }
    __syncthreads();

    uint4 bb[2][4];   // [buf][s*2+nt]
    float dh[2][2];
    {   // prefetch step 0
        #pragma unroll
        for (int s = 0; s < 2; ++s)
            #pragma unroll
            for (int nt = 0; nt < 2; ++nt) {
                int jr = jstart + wn * 32 + nt * 16 + l16;
                bb[0][s * 2 + nt] = reinterpret_cast<const uint4*>(d_hi + (size_t)jr * 64)[s * 4 + quad];
            }
        #pragma unroll
        for (int nt = 0; nt < 2; ++nt)
            dh[0][nt] = dnh[jstart + wn * 32 + nt * 16 + l16];
    }

    #pragma unroll 2
    for (int t = 0; t < JT4; ++t) {
        int cur = t & 1, nxt = cur ^ 1;
        if (t + 1 < JT4) {               // prefetch next step
            int jb = jstart + (t + 1) * 64;
            #pragma unroll
            for (int s = 0; s < 2; ++s)
                #pragma unroll
                for (int nt = 0; nt < 2; ++nt) {
                    int jr = jb + wn * 32 + nt * 16 + l16;
                    bb[nxt][s * 2 + nt] = reinterpret_cast<const uint4*>(d_hi + (size_t)jr * 64)[s * 4 + quad];
                }
            #pragma unroll
            for (int nt = 0; nt < 2; ++nt)
                dh[nxt][nt] = dnh[jb + wn * 32 + nt * 16 + l16];
        }

        floatx4 acc[4][2];
        #pragma unroll
        for (int mt = 0; mt < 4; ++mt) {
            floatx4 cv = (floatx4){scv[mt][0], scv[mt][1], scv[mt][2], scv[mt][3]};
            acc[mt][0] = cv;
            acc[mt][1] = cv;
        }
        #pragma unroll
        for (int s = 0; s < 2; ++s) {
            U16 u0, u1;
            u0.u = bb[cur][s * 2 + 0];
            u1.u = bb[cur][s * 2 + 1];
            #pragma unroll
            for (int mt = 0; mt < 4; ++mt) {
                acc[mt][0] = __builtin_amdgcn_mfma_f32_16x16x32_bf16(af[s][mt], u0.v, acc[mt][0], 0, 0, 0);
                acc[mt][1] = __builtin_amdgcn_mfma_f32_16x16x32_bf16(af[s][mt], u1.v, acc[mt][1], 0, 0, 0);
            }
        }

        int jb = jstart + t * 64;
        #pragma unroll
        for (int nt = 0; nt < 2; ++nt) {
            int j = jb + wn * 32 + nt * 16 + l16;
            float dd = dh[cur][nt];      // INF for pad cols -> never pass
            #pragma unroll
            for (int mt = 0; mt < 4; ++mt) {
                floatx4 a4 = acc[mt][nt];
                bool p0 = a4[0] >= dd, p1 = a4[1] >= dd;
                bool p2 = a4[2] >= dd, p3 = a4[3] >= dd;
                if (p0 | p1 | p2 | p3) {
                    #pragma unroll
                    for (int rg = 0; rg < 4; ++rg) {
                        bool pp = (rg == 0) ? p0 : (rg == 1) ? p1 : (rg == 2) ? p2 : p3;
                        if (pp) {
                            int mloc = wm * 64 + mt * 16 + quad * 4 + rg;
                            float delta = 2.0f * (dd - a4[rg]);  // sqb - (thr+2S)
                            int pos = atomicAdd(&lcnt[mloc], 1);
                            if (pos < LCAP) {
                                lbd[mloc][pos] = delta;
                                lbj[mloc][pos] = j;
                            } else {                              // rare overflow
                                int row = m0 + mloc;
                                int gp = atomicAdd(&cnt[row], 1);
                                if (gp < CAP) {
                                    bufd[(size_t)row * CAP + gp] = sts[mloc] + delta;
                                    bufi[(size_t)row * CAP + gp] = j;
                                }
                            }
                        }
                    }
                }
            }
        }
    }
    __syncthreads();
    if (tid < 128) {
        int c = lcnt[tid];
        if (c > LCAP) c = LCAP;
        if (c > 0) {
            int row = m0 + tid;
            float ts = sts[tid];
            int base = atomicAdd(&cnt[row], c);
            for (int i = 0; i < c; ++i) {
                int gp = base + i;
                if (gp < CAP) {
                    bufd[(size_t)row * CAP + gp] = ts + lbd[tid][i];
                    bufi[(size_t)row * CAP + gp] = lbj[tid][i];
                }
            }
        }
    }
}

// --------------------------------------------------------- select + finish --
__global__ __launch_bounds__(64) void select_finish(const float* __restrict__ bufd,
                                                    const int* __restrict__ bufi,
                                                    const int* __restrict__ cnt,
                                                    const float* __restrict__ xs,
                                                    const float* __restrict__ xnorm,
                                                    const float* __restrict__ dnorm,
                                                    const float* __restrict__ data,
                                                    const float* __restrict__ xdot,
                                                    const float* __restrict__ vel,
                                                    float* __restrict__ out) {
    __shared__ float sd[CAP];
    __shared__ int   si[CAP];
    __shared__ float sx[64];
    __shared__ float se[SSEL];
    __shared__ int   sj[SSEL];
    __shared__ int   scnt;
    __shared__ float seld[KK];
    __shared__ int   seli[KK];
    __shared__ float selw[KK];
    int row = blockIdx.x, lane = threadIdx.x;
    int n = cnt[row];
    if (n > CAP) n = CAP;
    for (int i = lane; i < n; i += 64) {
        sd[i] = bufd[(size_t)row * CAP + i];
        si[i] = bufi[(size_t)row * CAP + i];
    }
    sx[lane] = xs[row * 64 + lane];
    if (lane == 0) scnt = 0;
    __syncthreads();

    // T = exact 20th smallest of clamped approx sq -- bitwise bisection
    unsigned res = 0;
    for (int b = 30; b >= 0; --b) {
        unsigned cand = res | (1u << b);
        int c = 0;
        for (int i = lane; i < n; i += 64)
            c += (__float_as_uint(fmaxf(sd[i], 0.f)) < cand);
        c = wsum64i(c);
        if (c <= KK - 1) res = cand;
    }
    float T = __uint_as_float(res);

    // band {approx <= T + 2*SLACK} is a superset of the exact top-20
    for (int i = lane; i < n; i += 64) {
        if (sd[i] <= T + 2.0f * SLACK) {
            int q = atomicAdd(&scnt, 1);
            if (q < SSEL) sj[q] = si[i];
        }
    }
    __syncthreads();
    int m = scnt < SSEL ? scnt : SSEL;
    // exact fp32 recompute (bit-identical chain: sequential fmaf, k ascending)
    for (int c = lane; c < m; c += 64) {
        int j = sj[c];
        const float4* dp = reinterpret_cast<const float4*>(data + (size_t)j * 64);
        float dot = 0.f;
        #pragma unroll
        for (int kb = 0; kb < 16; ++kb) {
            float4 q = dp[kb];
            dot = fmaf(sx[kb * 4 + 0], q.x, dot);
            dot = fmaf(sx[kb * 4 + 1], q.y, dot);
            dot = fmaf(sx[kb * 4 + 2], q.z, dot);
            dot = fmaf(sx[kb * 4 + 3], q.w, dot);
        }
        se[c] = xnorm[row] + dnorm[j] - 2.0f * dot;
    }
    __syncthreads();
    // exact top-20, tie-break smaller index (matches lax.top_k)
    for (int k = 0; k < KK; ++k) {
        float v = INF_F; int id = 0x7fffffff; int p = -1;
        for (int i = lane; i < m; i += 64) {
            float x = se[i]; int xi = sj[i];
            if (x < v || (x == v && xi < id)) { v = x; id = xi; p = i; }
        }
        #pragma unroll
        for (int o = 32; o > 0; o >>= 1) {
            float ov = __shfl_xor(v, o, 64);
            int oid = __shfl_xor(id, o, 64);
            int op  = __shfl_xor(p, o, 64);
            if (ov < v || (ov == v && oid < id)) { v = ov; id = oid; p = op; }
        }
        if (lane == 0) {
            seld[k] = v; seli[k] = id;
            if (p >= 0) se[p] = INF_F;
        }
        __syncthreads();
    }
    float d20 = sqrtf(fmaxf(seld[KK - 1], 1e-30f));
    float h = fmaxf(d20, 1e-12f);
    float wk = 0.f;
    if (lane < KK) {
        float dd = sqrtf(fmaxf(seld[lane], 1e-30f));
        wk = expf(-(dd * dd) / (2.f * h * h));
    }
    float tot = wsum64(wk) + 1e-12f;
    if (lane < KK) selw[lane] = wk / tot;
    __syncthreads();
    float u = 0.f;
    #pragma unroll
    for (int k = 0; k < KK; ++k)
        u = fmaf(selw[k], vel[(size_t)seli[k] * 64 + lane], u);
    float xd = xdot[(size_t)row * 64 + lane];
    float du  = wsum64(u * xd);
    float nu2 = wsum64(u * u);
    float nx2 = wsum64(xd * xd);
    float l2  = wsum64((u - xd) * (u - xd));
    float nu = fmaxf(sqrtf(nu2), 1e-8f);
    float nx = fmaxf(sqrtf(nx2), 1e-8f);
    out[(size_t)row * 66 + lane] = xd;
    if (lane == 0) {
        out[(size_t)row * 66 + 64] = 1.f - du / (nu * nx);
        out[(size_t)row * 66 + 65] = l2;
    }
}

// ---------------------------------------------------------------------------
extern "C" void kernel_launch(void* const* d_in, const int* in_sizes, int n_in,
                              void* d_out, int out_size, void* d_ws, size_t ws_size,
                              hipStream_t stream) {
    const float* t_   = (const float*)d_in[0];
    const float* z    = (const float*)d_in[1];
    const float* data = (const float*)d_in[2];
    const float* vel  = (const float*)d_in[3];
    const float* W1   = (const float*)d_in[4];
    const float* b1   = (const float*)d_in[5];
    const float* W2   = (const float*)d_in[6];
    const float* b2   = (const float*)d_in[7];
    float* out = (float*)d_out;

    // workspace layout (floats, 16B-aligned); total ~47 MB
    float*  xs    = (float*)d_ws;                     // 131072
    float*  xnorm = xs + 131072;                      // 2048
    float*  thr   = xnorm + 2048;                     // 2048
    int*    cnt   = (int*)(thr + 2048);               // 2048
    float*  xdot  = (float*)(cnt + 2048);             // 131072
    float*  dnorm = xdot + 131072;                    // 100352
    float*  dnh   = dnorm + NPAD2;                    // 100352
    __bf16* xs_h  = (__bf16*)(dnh + NPAD2);           // 131072 bf16
    __bf16* d_hi  = xs_h + 131072;                    // NPAD2*64 bf16
    unsigned short* samp16 = (unsigned short*)(d_hi + (size_t)NPAD2 * 64); // 2048*8192 u16 = 32MB
    float*  bufd  = (float*)samp16;                   // overlap: samp16 dead first
    int*    bufi  = (int*)(bufd + (size_t)B * CAP);   // 2048*1024

    setup_all<<<NB_DATA + NB_PREP + NB_MLP, 256, 0, stream>>>(
        z, t_, data, W1, b1, W2, b2, xs, xnorm, xs_h, cnt, dnorm, dnh, d_hi, xdot);
    sample_gemm<<<1024, 256, 0, stream>>>(xs_h, d_hi, xnorm, dnorm, samp16);
    thr_select<<<B / 4, 256, 0, stream>>>(samp16, thr);
    gemm_filter<<<16 * JGRP2P, 256, 0, stream>>>(
        xs_h, d_hi, xnorm, dnh, thr, cnt, bufd, bufi);
    select_finish<<<B, 64, 0, stream>>>(bufd, bufi, cnt, xs, xnorm, dnorm, data,
                                        xdot, vel, out);
    (void)ws_size; (void)in_sizes; (void)n_in; (void)out_size;
}